// Round 3
// baseline (527.315 us; speedup 1.0000x reference)
//
#include <hip/hip_runtime.h>
#include <hip/hip_bf16.h>
#include <cstdint>
#include <cstddef>

#define N_NODES 200000
#define DIM 256
#define P_EDGES 65536
#define INV_TEMP 5.0f
#define NBLK_EDGE (P_EDGES / 16)   // 4096 blocks, 16 edges/block (16-lane groups)

typedef __attribute__((ext_vector_type(8))) short short8;
typedef __attribute__((ext_vector_type(4))) float f32x4;

__device__ __forceinline__ unsigned short f2bf(float f) {
    unsigned int x = __float_as_uint(f);
    x = (x + 0x7FFFu + ((x >> 16) & 1u)) >> 16;   // RNE (inputs finite)
    return (unsigned short)x;
}
__device__ __forceinline__ float bf2f(unsigned short u) {
    return __uint_as_float(((unsigned int)u) << 16);
}

// ---------------------------------------------------------------------------
// Kernel 1: W_src/W_dst f32 -> bf16 (row-major [out_feat][k], i.e. W as given:
// nn.Linear does x @ W^T, so W rows are output features -> contiguous k). 
// ---------------------------------------------------------------------------
__global__ void convert_w(const float* __restrict__ Wsrc, const float* __restrict__ Wdst,
                          unsigned short* __restrict__ Wsb, unsigned short* __restrict__ Wdb) {
    int g = blockIdx.x * blockDim.x + threadIdx.x;      // 0..32767 float4 granules
    const float4* src;
    unsigned short* dst;
    int off;
    if (g < 16384) { src = (const float4*)Wsrc; dst = Wsb; off = g; }
    else           { src = (const float4*)Wdst; dst = Wdb; off = g - 16384; }
    float4 v = src[off];
    ushort4 h;
    h.x = f2bf(v.x); h.y = f2bf(v.y); h.z = f2bf(v.z); h.w = f2bf(v.w);
    *reinterpret_cast<ushort4*>(dst + (size_t)off * 4) = h;
}

// ---------------------------------------------------------------------------
// Kernel 2: Zs = l2norm_rows(emb @ Wsrc^T), Zd = l2norm_rows(emb @ Wdst^T),
// both bf16, ONE pass over emb. 512 threads = 8 waves; block = 64 nodes.
// Wave wv: matrix (wv>>2), feature quadrant (wv&3)*64. Per wave: 4 node-tiles
// x 4 feat-tiles of mfma_f32_16x16x32_bf16 with SWAPPED operands
// (A = W-frag, B = emb-frag) so D: col(lane&15)=node, row(grp*4+r)=feature.
// => each lane holds 4 consecutive features of one node -> ushort4 stores
// covering full 32B sectors (no LDS transpose, no strided u16 scatter).
// ---------------------------------------------------------------------------
__global__ __launch_bounds__(512) void proj_gemm(
    const float* __restrict__ emb,
    const unsigned short* __restrict__ Wsb,
    const unsigned short* __restrict__ Wdb,
    unsigned short* __restrict__ Zs,
    unsigned short* __restrict__ Zd)
{
    __shared__ unsigned short As[64][264];   // +8 u16 pad: 528B row stride
    __shared__ float partial[8][64];         // [wave][node] quadrant sum-of-squares
    const int row0 = blockIdx.x * 64;

    // ---- stage 64x256 f32 -> bf16 LDS, fully coalesced float4 loads ----
    {
        const float4* e4 = (const float4*)(emb + (size_t)row0 * DIM);
        const int t = threadIdx.x;
        #pragma unroll
        for (int i = 0; i < 8; ++i) {
            const int g = i * 512 + t;              // 0..4095 granules
            float4 v = e4[g];
            ushort4 h;
            h.x = f2bf(v.x); h.y = f2bf(v.y); h.z = f2bf(v.z); h.w = f2bf(v.w);
            *reinterpret_cast<ushort4*>(&As[g >> 6][(g & 63) * 4]) = h;
        }
    }
    __syncthreads();

    const int lane = threadIdx.x & 63;
    const int wv = threadIdx.x >> 6;       // 0..7
    const int mat = wv >> 2;               // 0: src, 1: dst
    const int cq = wv & 3;                 // 64-feature quadrant
    const int l15 = lane & 15;
    const int grp = lane >> 4;

    const unsigned short* __restrict__ W = mat ? Wdb : Wsb;
    unsigned short* __restrict__ out = mat ? Zd : Zs;

    f32x4 acc[4][4];   // [node-tile][feat-tile]
    #pragma unroll
    for (int nt = 0; nt < 4; ++nt)
        #pragma unroll
        for (int ft = 0; ft < 4; ++ft) acc[nt][ft] = (f32x4){0.f, 0.f, 0.f, 0.f};

    #pragma unroll
    for (int ks = 0; ks < 8; ++ks) {
        const int k0 = ks * 32 + grp * 8;
        short8 ef[4], wf[4];
        #pragma unroll
        for (int nt = 0; nt < 4; ++nt)
            ef[nt] = *reinterpret_cast<const short8*>(&As[nt * 16 + l15][k0]);
        #pragma unroll
        for (int ft = 0; ft < 4; ++ft)
            wf[ft] = *reinterpret_cast<const short8*>(
                W + (size_t)(cq * 64 + ft * 16 + l15) * DIM + k0);
        #pragma unroll
        for (int nt = 0; nt < 4; ++nt)
            #pragma unroll
            for (int ft = 0; ft < 4; ++ft)
                acc[nt][ft] = __builtin_amdgcn_mfma_f32_16x16x32_bf16(
                    wf[ft], ef[nt], acc[nt][ft], 0, 0, 0);
    }

    // ---- per-node sum-of-squares over this wave's 64 features ----
    // lane(grp,l15) holds node nt*16+l15, features cq*64 + ft*16 + grp*4 + r
    #pragma unroll
    for (int nt = 0; nt < 4; ++nt) {
        float ssq = 0.f;
        #pragma unroll
        for (int ft = 0; ft < 4; ++ft)
            #pragma unroll
            for (int r = 0; r < 4; ++r) { float x = acc[nt][ft][r]; ssq += x * x; }
        ssq += __shfl_xor(ssq, 16);        // reduce across grp groups
        ssq += __shfl_xor(ssq, 32);
        if (grp == 0) partial[wv][nt * 16 + l15] = ssq;
    }
    __syncthreads();

    // ---- normalize + store: ushort4 (4 consecutive features) per (nt,ft) ----
    #pragma unroll
    for (int nt = 0; nt < 4; ++nt) {
        const int node = nt * 16 + l15;
        const float tot = partial[mat * 4 + 0][node] + partial[mat * 4 + 1][node]
                        + partial[mat * 4 + 2][node] + partial[mat * 4 + 3][node];
        const float inv = rsqrtf(fmaxf(tot, 1e-24f));
        unsigned short* orow = out + (size_t)(row0 + node) * DIM + cq * 64 + grp * 4;
        #pragma unroll
        for (int ft = 0; ft < 4; ++ft) {
            ushort4 h;
            h.x = f2bf(acc[nt][ft][0] * inv);
            h.y = f2bf(acc[nt][ft][1] * inv);
            h.z = f2bf(acc[nt][ft][2] * inv);
            h.w = f2bf(acc[nt][ft][3] * inv);
            *reinterpret_cast<ushort4*>(orow + ft * 16) = h;
        }
    }
}

// ---------------------------------------------------------------------------
// Kernel 3: per-edge loss, one edge per 16-lane group (16 edges / 256-thr
// block). Per lane: 32 contiguous bytes of each row (2x b128 loads), 4-step
// shfl reduce. Per-block partial {sum(loss*use), sum(use)} -> ws (NO atomics;
// deterministic).
// ---------------------------------------------------------------------------
__global__ __launch_bounds__(256) void edge_loss(
    const unsigned short* __restrict__ Zs,
    const unsigned short* __restrict__ Zd,
    const int* __restrict__ pos_src, const int* __restrict__ pos_dst,
    const int* __restrict__ pos_sign,
    const int* __restrict__ neg_src, const int* __restrict__ neg_dst,
    float* __restrict__ partials)
{
    const int tid = threadIdx.x;
    const int l15 = tid & 15;
    const int g = tid >> 4;                      // group 0..15
    const int p = blockIdx.x * 16 + g;

    int su[9], sv[9];
    su[0] = pos_src[p]; sv[0] = pos_dst[p];
    #pragma unroll
    for (int k = 0; k < 8; ++k) { su[k + 1] = neg_src[p * 8 + k]; sv[k + 1] = neg_dst[p * 8 + k]; }

    float sims[9];
    #pragma unroll
    for (int j = 0; j < 9; ++j) {
        const unsigned short* ur = Zs + (size_t)su[j] * DIM + l15 * 16;
        const unsigned short* vr = Zd + (size_t)sv[j] * DIM + l15 * 16;
        short8 u0 = *reinterpret_cast<const short8*>(ur);
        short8 u1 = *reinterpret_cast<const short8*>(ur + 8);
        short8 v0 = *reinterpret_cast<const short8*>(vr);
        short8 v1 = *reinterpret_cast<const short8*>(vr + 8);
        float s = 0.f;
        #pragma unroll
        for (int i = 0; i < 8; ++i) {
            s += bf2f((unsigned short)u0[i]) * bf2f((unsigned short)v0[i]);
            s += bf2f((unsigned short)u1[i]) * bf2f((unsigned short)v1[i]);
        }
        s += __shfl_xor(s, 1);
        s += __shfl_xor(s, 2);
        s += __shfl_xor(s, 4);
        s += __shfl_xor(s, 8);
        sims[j] = s;
    }

    const int sg = pos_sign[p];
    float ln[9];
    ln[0] = (sg == 0 ? -sims[0] : sims[0]) * INV_TEMP;
    float m = ln[0];
    #pragma unroll
    for (int j = 1; j < 9; ++j) { ln[j] = sims[j] * INV_TEMP; m = fmaxf(m, ln[j]); }
    float se = 0.f;
    #pragma unroll
    for (int j = 0; j < 9; ++j) se += __expf(ln[j] - m);
    const float loss = m + __logf(se) - ln[0];
    const float use = (sg != 2) ? 1.f : 0.f;

    __shared__ float wl[16], wc[16];
    if (l15 == 0) { wl[g] = loss * use; wc[g] = use; }
    __syncthreads();
    if (tid == 0) {
        float L = 0.f, C = 0.f;
        #pragma unroll
        for (int i = 0; i < 16; ++i) { L += wl[i]; C += wc[i]; }
        partials[blockIdx.x * 2 + 0] = L;
        partials[blockIdx.x * 2 + 1] = C;
    }
}

// ---------------------------------------------------------------------------
// Kernel 4: reduce 4096 block-partials, write the scalar loss.
// ---------------------------------------------------------------------------
__global__ __launch_bounds__(256) void finalize(const float* __restrict__ partials,
                                                float* __restrict__ out) {
    const int tid = threadIdx.x;
    float L = 0.f, C = 0.f;
    for (int i = tid; i < NBLK_EDGE; i += 256) {
        L += partials[i * 2 + 0];
        C += partials[i * 2 + 1];
    }
    #pragma unroll
    for (int s = 32; s >= 1; s >>= 1) {
        L += __shfl_xor(L, s);
        C += __shfl_xor(C, s);
    }
    __shared__ float sl[4], sc[4];
    if ((tid & 63) == 0) { sl[tid >> 6] = L; sc[tid >> 6] = C; }
    __syncthreads();
    if (tid == 0) {
        float Lt = sl[0] + sl[1] + sl[2] + sl[3];
        float Ct = sc[0] + sc[1] + sc[2] + sc[3];
        out[0] = Lt / (Ct + 1e-9f);
    }
}

// ---------------------------------------------------------------------------
extern "C" void kernel_launch(void* const* d_in, const int* in_sizes, int n_in,
                              void* d_out, int out_size, void* d_ws, size_t ws_size,
                              hipStream_t stream) {
    const float* node_emb = (const float*)d_in[0];
    const float* W_src    = (const float*)d_in[1];
    const float* W_dst    = (const float*)d_in[2];
    const int* pos_src    = (const int*)d_in[3];
    const int* pos_dst    = (const int*)d_in[4];
    const int* pos_sign   = (const int*)d_in[5];
    const int* neg_src    = (const int*)d_in[6];
    const int* neg_dst    = (const int*)d_in[7];
    float* out = (float*)d_out;

    char* ws = (char*)d_ws;
    const size_t zbytes = (size_t)N_NODES * DIM * 2;           // 102,400,000 B each
    unsigned short* Zs  = (unsigned short*)ws;
    unsigned short* Zd  = (unsigned short*)(ws + zbytes);
    unsigned short* Wsb = (unsigned short*)(ws + 2 * zbytes);
    unsigned short* Wdb = Wsb + DIM * DIM;
    float* partials = (float*)(Wdb + DIM * DIM);               // 4096*2 f32 = 32 KB

    hipLaunchKernelGGL(convert_w, dim3(128), dim3(256), 0, stream,
                       W_src, W_dst, Wsb, Wdb);
    hipLaunchKernelGGL(proj_gemm, dim3(N_NODES / 64), dim3(512), 0, stream,
                       node_emb, Wsb, Wdb, Zs, Zd);
    hipLaunchKernelGGL(edge_loss, dim3(NBLK_EDGE), dim3(256), 0, stream,
                       Zs, Zd, pos_src, pos_dst, pos_sign, neg_src, neg_dst, partials);
    hipLaunchKernelGGL(finalize, dim3(1), dim3(256), 0, stream, partials, out);
}